// Round 1
// baseline (41.029 us; speedup 1.0000x reference)
//
#include <hip/hip_runtime.h>
#include <math.h>

#define HWSZ 262144          // 512*512
#define NCOPY 16             // partial-G copies to spread atomics
#define LAMBD 0.005f
#define SMOOTH 1e-6f

typedef __attribute__((ext_vector_type(8))) short bf16x8;
typedef __attribute__((ext_vector_type(4))) float f32x4;

static __device__ __forceinline__ unsigned short f2bf(float f) {
    unsigned int u = __float_as_uint(f);
    u += 0x7FFFu + ((u >> 16) & 1u);   // round-to-nearest-even
    return (unsigned short)(u >> 16);
}

// Stage bf16 W-tiles ([32 rows] = 16 batches of P then 16 of Q) in LDS,
// accumulate G = W W^T via 16x16x32 bf16 MFMA. 264-short row stride keeps
// both ds_write_b128 and ds_read_b128 at the structural 8-cycle floor.
__global__ __launch_bounds__(256) void gram_kernel(
    const float* __restrict__ X,   // input  [16][4][512][512]
    const float* __restrict__ T,   // target [16][4][512][512]
    float* __restrict__ Gpart)     // [NCOPY][32][32]
{
    __shared__ unsigned short w[32][264];

    const int tid  = threadIdx.x;
    const int b    = tid >> 4;             // batch 0..15 (producer role)
    const int px4  = (tid & 15) << 2;      // pixel offset within tile, x4
    const int lane = tid & 63;
    const int wv   = tid >> 6;
    const int r    = lane & 15;
    const int g    = lane >> 4;
    const int I    = (wv >> 1) << 4;       // G row tile base
    const int J    = (wv & 1) << 4;        // G col tile base

    f32x4 acc = {0.f, 0.f, 0.f, 0.f};

    const int tile0 = blockIdx.x << 2;     // 4 tiles of 64 pixels per block
    for (int ti = 0; ti < 4; ++ti) {
        const int pixBase = (tile0 + ti) << 6;

        // ---- global loads: 4 pixels x 4 channels x {input,target} ----
        float fi[16], ft[16];
        #pragma unroll
        for (int c = 0; c < 4; ++c) {
            size_t off = (size_t)(b * 4 + c) * HWSZ + pixBase + px4;
            *(float4*)&fi[c * 4] = *(const float4*)(X + off);
            *(float4*)&ft[c * 4] = *(const float4*)(T + off);
        }

        // ---- per-pixel softplus/confidence/softmax (f32), pack bf16 ----
        unsigned short pv[16] __attribute__((aligned(16)));
        unsigned short qv[16] __attribute__((aligned(16)));
        #pragma unroll
        for (int p = 0; p < 4; ++p) {
            float t0 = ft[p], t1 = ft[4 + p], t2 = ft[8 + p], t3 = ft[12 + p];
            // stable softplus: max(t,0) + log(1 + exp(-|t|))
            float sp0 = fmaxf(t0, 0.f) + __logf(1.f + __expf(-fabsf(t0)));
            float sp1 = fmaxf(t1, 0.f) + __logf(1.f + __expf(-fabsf(t1)));
            float sp2 = fmaxf(t2, 0.f) + __logf(1.f + __expf(-fabsf(t2)));
            float sp3 = fmaxf(t3, 0.f) + __logf(1.f + __expf(-fabsf(t3)));
            float S    = sp0 + sp1 + sp2 + sp3 + 4.0f;   // mm_S
            float conf = __expf(-4.0f / S);

            // p = softmax(input) (the +1 shift cancels)
            float x0 = fi[p], x1 = fi[4 + p], x2 = fi[8 + p], x3 = fi[12 + p];
            float mx = fmaxf(fmaxf(x0, x1), fmaxf(x2, x3));
            float e0 = __expf(x0 - mx), e1 = __expf(x1 - mx);
            float e2 = __expf(x2 - mx), e3 = __expf(x3 - mx);
            float inv = 1.f / (e0 + e1 + e2 + e3);
            pv[p * 4 + 0] = f2bf(e0 * inv);
            pv[p * 4 + 1] = f2bf(e1 * inv);
            pv[p * 4 + 2] = f2bf(e2 * inv);
            pv[p * 4 + 3] = f2bf(e3 * inv);

            // q = softmax((target+1)*conf)
            float y0 = (t0 + 1.f) * conf, y1 = (t1 + 1.f) * conf;
            float y2 = (t2 + 1.f) * conf, y3 = (t3 + 1.f) * conf;
            float my = fmaxf(fmaxf(y0, y1), fmaxf(y2, y3));
            float q0 = __expf(y0 - my), q1 = __expf(y1 - my);
            float q2 = __expf(y2 - my), q3 = __expf(y3 - my);
            float qi = 1.f / (q0 + q1 + q2 + q3);
            qv[p * 4 + 0] = f2bf(q0 * qi);
            qv[p * 4 + 1] = f2bf(q1 * qi);
            qv[p * 4 + 2] = f2bf(q2 * qi);
            qv[p * 4 + 3] = f2bf(q3 * qi);
        }

        __syncthreads();   // previous iteration's MFMA reads complete
        // column k = px*4 + c  (contiguous 16 shorts per thread per row)
        *(bf16x8*)&w[b][px4 * 4]          = *(const bf16x8*)&pv[0];
        *(bf16x8*)&w[b][px4 * 4 + 8]      = *(const bf16x8*)&pv[8];
        *(bf16x8*)&w[16 + b][px4 * 4]     = *(const bf16x8*)&qv[0];
        *(bf16x8*)&w[16 + b][px4 * 4 + 8] = *(const bf16x8*)&qv[8];
        __syncthreads();

        // ---- MFMA: this wave's 16x16 tile of G over K=256 ----
        #pragma unroll
        for (int kc = 0; kc < 8; ++kc) {
            bf16x8 a  = *(const bf16x8*)&w[I + r][kc * 32 + g * 8];
            bf16x8 bb = *(const bf16x8*)&w[J + r][kc * 32 + g * 8];
            acc = __builtin_amdgcn_mfma_f32_16x16x32_bf16(a, bb, acc, 0, 0, 0);
        }
    }

    // C/D layout: col = lane&15, row = (lane>>4)*4 + reg
    float* dst = Gpart + (size_t)(blockIdx.x & (NCOPY - 1)) * 1024;
    #pragma unroll
    for (int v = 0; v < 4; ++v) {
        int row = I + g * 4 + v;
        int col = J + r;
        atomicAdd(&dst[row * 32 + col], acc[v]);
    }
}

__global__ __launch_bounds__(256) void loss_kernel(
    const float* __restrict__ Gpart, float* __restrict__ out)
{
    __shared__ float G[1024];
    __shared__ float red[4];
    const int t = threadIdx.x;

    for (int e = t; e < 1024; e += 256) {
        float s = 0.f;
        #pragma unroll
        for (int c = 0; c < NCOPY; ++c) s += Gpart[c * 1024 + e];
        G[e] = s;
    }
    __syncthreads();

    float local = 0.f;
    for (int e = t; e < 1024; e += 256) {
        int i = e >> 5, j = e & 31;
        float num = 2.f * G[(i << 5) | (j ^ 16)] + SMOOTH;
        float den = G[i * 33] + G[(j ^ 16) * 33] + SMOOTH;
        float D = num / den;
        if (j == (i ^ 16)) D = 0.f;                      // mask (i, i±B)
        local += (i == j) ? (D - 1.f) * (D - 1.f) : LAMBD * D * D;
    }

    #pragma unroll
    for (int off = 32; off; off >>= 1) local += __shfl_down(local, off);
    if ((t & 63) == 0) red[t >> 6] = local;
    __syncthreads();
    if (t == 0) out[0] = red[0] + red[1] + red[2] + red[3];
}

extern "C" void kernel_launch(void* const* d_in, const int* in_sizes, int n_in,
                              void* d_out, int out_size, void* d_ws, size_t ws_size,
                              hipStream_t stream)
{
    const float* X = (const float*)d_in[0];   // input
    const float* T = (const float*)d_in[1];   // target
    float* Gpart = (float*)d_ws;              // NCOPY * 1024 floats

    hipMemsetAsync(Gpart, 0, NCOPY * 1024 * sizeof(float), stream);
    gram_kernel<<<1024, 256, 0, stream>>>(X, T, Gpart);
    loss_kernel<<<1, 256, 0, stream>>>(Gpart, (float*)d_out);
}